// Round 8
// baseline (181.587 us; speedup 1.0000x reference)
//
#include <hip/hip_runtime.h>
#include <hip/hip_bf16.h>

#define B_DIM 4
#define C_DIM 192
#define T_SEQ 2048
#define H_DIM 2
#define K_DIM 96
#define BAND 256
#define IT 16            // q rows per attn block
#define WSLOT 544        // padded window slots (wlen <= 528), 34 tiles of 16
#define W_P 548          // p_s row stride in dwords (16B aligned, +4 bank skew)
#define PMW 17           // packed-mask words per row

typedef __attribute__((ext_vector_type(8))) short bf16x8;
typedef __attribute__((ext_vector_type(4))) short bf16x4;
typedef __attribute__((ext_vector_type(4))) float f32x4;
#define MFMA16 __builtin_amdgcn_mfma_f32_16x16x32_bf16

__device__ __forceinline__ float bfbits2f(short s) {
    union { short s; __hip_bfloat16 h; } u; u.s = s; return __bfloat162float(u.h);
}
__device__ __forceinline__ short f2bf_bits(float f) {
    union { __hip_bfloat16 h; short s; } u; u.h = __float2bfloat16(f); return u.s;
}

// ---- workspace layout (bytes) ----
#define OFF_WT(m)  ((size_t)(m)*73728)          // WqT|WkT|WvT|WoT bf16 [192][192]
#define OFF_BQS    ((size_t)294912)             // fp32[192] scaled bq
#define OFF_RELKBF ((size_t)295680)             // bf16[16][96], rows 9..15 zero
#define OFF_LT     ((size_t)298752)             // fp32[257] log1p table
#define OFF_PM     ((size_t)299840)             // u32[B*T*17] packed mask bits
#define OFF_QBF    ((size_t)856896)             // bf16 [bh][t][96]
#define OFF_KBF    (OFF_QBF + 3145728)
#define OFF_VTB    (OFF_KBF + 3145728)          // bf16 [bh][96][t]
#define OFF_OBTC   (OFF_VTB + 3145728)          // bf16 [b][t][192]

// ---------------------------------------------------------------------------
// Prep (fused): [0,576) weight transpose; [576,1120) mask bit-pack;
// 1120: scaled bias + bf16 rel-k table + log1p table.
// ---------------------------------------------------------------------------
__global__ __launch_bounds__(256)
void prep_kernel(const float* __restrict__ Wq, const float* __restrict__ Wk,
                 const float* __restrict__ Wv, const float* __restrict__ Wo,
                 const float* __restrict__ bq, const float* __restrict__ relk,
                 const int* __restrict__ mask, char* __restrict__ ws)
{
    const float qscale = 0.10206207261596577f;
    const int bidx = blockIdx.x;
    const int tid  = threadIdx.x;

    if (bidx < 576) {                       // ---- weight transpose
        const size_t idx = (size_t)bidx*256 + tid;
        const int mi  = (int)(idx / 36864);
        const int rem = (int)(idx % 36864);
        const int c = rem / C_DIM, d = rem % C_DIM;   // coalesced read over d
        const float* src = (mi == 0) ? Wq : (mi == 1) ? Wk : (mi == 2) ? Wv : Wo;
        float v = src[c*C_DIM + d];
        if (mi == 0) v *= qscale;
        ((short*)(ws + OFF_WT(mi)))[d*C_DIM + c] = f2bf_bits(v);
        return;
    }
    if (bidx < 1120) {                      // ---- mask pack
        const int idx = (bidx - 576)*256 + tid;        // B*T*17 = 139264
        const int b = idx / (T_SEQ*PMW);
        const int rem = idx % (T_SEQ*PMW);
        const int i = rem / PMW, w = rem % PMW;
        const int jlo = max(0, (i & ~15) - BAND);
        const int* mrow = mask + ((size_t)b*T_SEQ + i)*T_SEQ;
        unsigned bits = 0;
        #pragma unroll
        for (int g4 = 0; g4 < 8; ++g4) {
            const int jg = jlo + 32*w + 4*g4;
            if (jg + 3 < T_SEQ) {
                const int4 mv = *reinterpret_cast<const int4*>(mrow + jg);
                bits |= (unsigned)(mv.x != 0) << (4*g4);
                bits |= (unsigned)(mv.y != 0) << (4*g4+1);
                bits |= (unsigned)(mv.z != 0) << (4*g4+2);
                bits |= (unsigned)(mv.w != 0) << (4*g4+3);
            } else {
                #pragma unroll
                for (int e = 0; e < 4; ++e)
                    if (jg + e < T_SEQ && mrow[jg+e] != 0) bits |= 1u << (4*g4+e);
            }
        }
        ((unsigned*)(ws + OFF_PM))[idx] = bits;
        return;
    }
    // ---- bias + rel-k table + log1p table
    if (tid < C_DIM)
        ((float*)(ws + OFF_BQS))[tid] = bq[tid]*qscale;
    short* rkb = (short*)(ws + OFF_RELKBF);
    for (int idx = tid; idx < 16*K_DIM; idx += 256) {
        const int row = idx / K_DIM;
        rkb[idx] = (row < 9) ? f2bf_bits(relk[idx]) : (short)0;
    }
    float* ltws = (float*)(ws + OFF_LT);
    for (int idx = tid; idx < 257; idx += 256) ltws[idx] = log1pf((float)idx);
}

// ---------------------------------------------------------------------------
// Kernel 1: q/k/v projection, bf16 MFMA. Block = (b, 16 t, d-half), 4 waves.
// Grid 1024 -> 4 blocks/CU for latency hiding. Waves take tiles 2/2/1/1.
// ---------------------------------------------------------------------------
__global__ __launch_bounds__(256)
void proj_kernel(const float* __restrict__ x, const float* __restrict__ cin,
                 const float* __restrict__ bk, const float* __restrict__ bv,
                 char* __restrict__ ws)
{
    __shared__ short xs[IT*C_DIM];   // [t][c] bf16
    __shared__ short cs[IT*C_DIM];
    const int b    = blockIdx.x >> 8;
    const int half = (blockIdx.x >> 7) & 1;
    const int t0   = (blockIdx.x & 127) * IT;
    const int tid  = threadIdx.x;
    const int wave = tid >> 6, lane = tid & 63;
    const int q4 = lane >> 4, lr = lane & 15;

    for (int l = tid; l < 768; l += 256) {
        const int cr = l >> 2, u = l & 3;
        const size_t off = (size_t)(b*C_DIM + cr)*T_SEQ + t0 + 4*u;
        const float4 xv = *reinterpret_cast<const float4*>(x + off);
        const float4 cv = *reinterpret_cast<const float4*>(cin + off);
        xs[(4*u+0)*C_DIM + cr] = f2bf_bits(xv.x);
        xs[(4*u+1)*C_DIM + cr] = f2bf_bits(xv.y);
        xs[(4*u+2)*C_DIM + cr] = f2bf_bits(xv.z);
        xs[(4*u+3)*C_DIM + cr] = f2bf_bits(xv.w);
        cs[(4*u+0)*C_DIM + cr] = f2bf_bits(cv.x);
        cs[(4*u+1)*C_DIM + cr] = f2bf_bits(cv.y);
        cs[(4*u+2)*C_DIM + cr] = f2bf_bits(cv.z);
        cs[(4*u+3)*C_DIM + cr] = f2bf_bits(cv.w);
    }
    __syncthreads();

    const short* WqT = (const short*)(ws + OFF_WT(0));
    const short* WkT = (const short*)(ws + OFF_WT(1));
    const short* WvT = (const short*)(ws + OFF_WT(2));
    const float* bqs = (const float*)(ws + OFF_BQS);
    short* qbf = (short*)(ws + OFF_QBF);
    short* kbf = (short*)(ws + OFF_KBF);
    short* vtb = (short*)(ws + OFF_VTB);

    #pragma unroll
    for (int u = 0; u < 2; ++u) {
        if (u == 1 && wave >= 2) break;
        const int tl = (u == 0) ? wave : wave + 4;   // local tile 0..5
        const int dt = half*6 + tl;                  // global d-tile 0..11
        f32x4 qa = {0,0,0,0}, ka = {0,0,0,0}, va = {0,0,0,0};
        #pragma unroll
        for (int kc = 0; kc < 6; ++kc) {
            const int ko = kc*32 + q4*8;
            const bf16x8 xf = *reinterpret_cast<const bf16x8*>(xs + lr*C_DIM + ko);
            const bf16x8 cf = *reinterpret_cast<const bf16x8*>(cs + lr*C_DIM + ko);
            const bf16x8 wqf = *reinterpret_cast<const bf16x8*>(WqT + (dt*16 + lr)*C_DIM + ko);
            const bf16x8 wkf = *reinterpret_cast<const bf16x8*>(WkT + (dt*16 + lr)*C_DIM + ko);
            const bf16x8 wvf = *reinterpret_cast<const bf16x8*>(WvT + (dt*16 + lr)*C_DIM + ko);
            qa = MFMA16(xf, wqf, qa, 0, 0, 0);   // m=t, n=d
            ka = MFMA16(cf, wkf, ka, 0, 0, 0);
            va = MFMA16(wvf, cf, va, 0, 0, 0);   // m=d, n=t
        }
        {   // q,k: col=d=dt*16+lr, row=t=q4*4+e
            const int d = dt*16 + lr, h = d/K_DIM, kk = d%K_DIM;
            const int bh = b*H_DIM + h;
            const float bq_v = bqs[d], bk_v = bk[d];
            #pragma unroll
            for (int e = 0; e < 4; ++e) {
                const int t = t0 + q4*4 + e;
                const size_t off = ((size_t)bh*T_SEQ + t)*K_DIM + kk;
                qbf[off] = f2bf_bits(qa[e] + bq_v);
                kbf[off] = f2bf_bits(ka[e] + bk_v);
            }
        }
        {   // v: col=t=lr, row=d=dt*16+q4*4+e
            #pragma unroll
            for (int e = 0; e < 4; ++e) {
                const int d = dt*16 + q4*4 + e, h = d/K_DIM, kk = d%K_DIM;
                const int bh = b*H_DIM + h;
                vtb[((size_t)bh*K_DIM + kk)*T_SEQ + t0 + lr] = f2bf_bits(va[e] + bv[d]);
            }
        }
    }
}

// ---------------------------------------------------------------------------
// Kernel 2: banded MFMA attention. Block = (b,h,16 rows), 4 waves.
// K/V tiles register-double-buffered; packed mask staged in LDS.
// ---------------------------------------------------------------------------
__global__ __launch_bounds__(256)
void attn_kernel(const float* __restrict__ relv, char* __restrict__ ws)
{
    __shared__ float p_s[IT*W_P];      // 35.1 KB raw scores -> bf16 probs
    __shared__ float shbuf[864];       // phase1: lt[257]@0, rl[144]@260; phase2: relv
    __shared__ unsigned pml[IT*PMW];   // 1.1 KB packed mask bits

    const short* qbf = (const short*)(ws + OFF_QBF);
    const short* kbf = (const short*)(ws + OFF_KBF);
    const short* vtb = (const short*)(ws + OFF_VTB);
    const short* rkb = (const short*)(ws + OFF_RELKBF);
    const float* ltws = (const float*)(ws + OFF_LT);
    const unsigned* pm = (const unsigned*)(ws + OFF_PM);
    short* obtc = (short*)(ws + OFF_OBTC);

    const int bh  = blockIdx.x >> 7;
    const int i0  = (blockIdx.x & 127) * IT;
    const int b   = bh / H_DIM;
    const int h   = bh % H_DIM;
    const int tid = threadIdx.x;
    const int wave = tid >> 6, lane = tid & 63;
    const int q4 = lane >> 4, lr = lane & 15;

    const int jlo  = max(0, i0 - BAND);
    const int jhi  = min(T_SEQ - 1, i0 + IT - 1 + BAND);
    const int wlen = jhi - jlo + 1;
    const size_t qkv_base = (size_t)bh * T_SEQ * K_DIM;

    float* lt = shbuf;
    float* rl = shbuf + 260;
    for (int idx = tid; idx < 257; idx += 256) lt[idx] = ltws[idx];
    for (int idx = tid; idx < IT*PMW; idx += 256)           // FIX: 272 words > 256 threads
        pml[idx] = pm[(b*T_SEQ + i0)*PMW + idx];

    // Q A-frags
    bf16x8 qa[3];
    {
        const short* qrow = qbf + qkv_base + (size_t)(i0 + lr)*K_DIM + q4*8;
        #pragma unroll
        for (int kc = 0; kc < 3; ++kc)
            qa[kc] = *reinterpret_cast<const bf16x8*>(qrow + kc*32);
    }

    // ---- scores: waves interleave j-tiles; K-tile register double-buffer
    {
        int jt = wave;
        const short* kr0;
        {
            int jr = jlo + jt*16 + lr;
            if (jr > T_SEQ-1) jr = T_SEQ-1;
            kr0 = kbf + qkv_base + (size_t)jr*K_DIM + q4*8;
        }
        bf16x8 kb0 = *reinterpret_cast<const bf16x8*>(kr0);
        bf16x8 kb1 = *reinterpret_cast<const bf16x8*>(kr0 + 32);
        bf16x8 kb2 = *reinterpret_cast<const bf16x8*>(kr0 + 64);
        while (jt < WSLOT/16) {
            const int jtn = jt + 4;
            bf16x8 n0, n1, n2;
            if (jtn < WSLOT/16) {
                int jr = jlo + jtn*16 + lr;
                if (jr > T_SEQ-1) jr = T_SEQ-1;
                const short* krn = kbf + qkv_base + (size_t)jr*K_DIM + q4*8;
                n0 = *reinterpret_cast<const bf16x8*>(krn);
                n1 = *reinterpret_cast<const bf16x8*>(krn + 32);
                n2 = *reinterpret_cast<const bf16x8*>(krn + 64);
            }
            f32x4 s = {0.f,0.f,0.f,0.f};
            s = MFMA16(qa[0], kb0, s, 0, 0, 0);
            s = MFMA16(qa[1], kb1, s, 0, 0, 0);
            s = MFMA16(qa[2], kb2, s, 0, 0, 0);
            #pragma unroll
            for (int e = 0; e < 4; ++e)
                p_s[(q4*4 + e)*W_P + jt*16 + lr] = s[e];
            kb0 = n0; kb1 = n1; kb2 = n2;
            jt = jtn;
        }
    }
    if (wave == 3) {                  // rl[r][dd] = q_r · relk_dd via MFMA
        const short* krow = rkb + lr*K_DIM + q4*8;
        f32x4 s = {0.f,0.f,0.f,0.f};
        #pragma unroll
        for (int kc = 0; kc < 3; ++kc)
            s = MFMA16(qa[kc], *reinterpret_cast<const bf16x8*>(krow + kc*32), s, 0, 0, 0);
        if (lr < 9) {
            #pragma unroll
            for (int e = 0; e < 4; ++e)
                rl[(q4*4 + e)*9 + lr] = s[e];
        }
    }
    __syncthreads();

    // ---- postprocess + softmax (row r by 16 lanes of its own wave)
    {
        const int r = tid >> 4, sj = tid & 15;
        const int i = i0 + r;
        float vals[36];
        float m = -INFINITY;
        #pragma unroll
        for (int mm = 0; mm < 9; ++mm) {
            const int j0 = 4*sj + 64*mm;
            float4 pv = make_float4(0.f,0.f,0.f,0.f);
            unsigned mb = 0;
            if (j0 < WSLOT) {
                pv = *reinterpret_cast<const float4*>(p_s + r*W_P + j0);
                mb = pml[r*PMW + (j0 >> 5)] >> (j0 & 31);
            }
            const float pe[4] = {pv.x, pv.y, pv.z, pv.w};
            #pragma unroll
            for (int e = 0; e < 4; ++e) {
                const int j = j0 + e;
                float val = -INFINITY;
                if (j0 < WSLOT && j < wlen) {
                    const int jg = jlo + j, dd = jg - i;
                    const int ad = dd < 0 ? -dd : dd;
                    if (ad <= BAND && ((mb >> e) & 1)) {
                        val = pe[e] - lt[ad];
                        if ((unsigned)(dd + 4) <= 8u) val += rl[r*9 + dd + 4];
                    }
                }
                vals[mm*4 + e] = val;
                m = fmaxf(m, val);
            }
        }
        #pragma unroll
        for (int off = 8; off > 0; off >>= 1) m = fmaxf(m, __shfl_xor(m, off, 64));
        if (m == -INFINITY) m = 0.f;
        float ssum = 0.f;
        #pragma unroll
        for (int u = 0; u < 36; ++u) { vals[u] = __expf(vals[u] - m); ssum += vals[u]; }
        #pragma unroll
        for (int off = 8; off > 0; off >>= 1) ssum += __shfl_xor(ssum, off, 64);
        const float inv = ssum > 0.f ? 1.f/ssum : 0.f;
        short* pb = (short*)p_s;
        #pragma unroll
        for (int mm = 0; mm < 9; ++mm) {
            const int j0 = 4*sj + 64*mm;
            if (j0 < WSLOT) {
                bf16x4 w;
                #pragma unroll
                for (int e = 0; e < 4; ++e) w[e] = f2bf_bits(vals[mm*4+e]*inv);
                *reinterpret_cast<bf16x4*>(pb + r*(2*W_P) + j0) = w;
            }
        }
    }
    __syncthreads();

    // ---- relv -> LDS (overwrites lt/rl) + PV with V double-buffer
    for (int idx = tid; idx < 9*K_DIM; idx += 256) shbuf[idx] = relv[idx];

    const short* pb = (const short*)p_s;
    f32x4 o0 = {0.f,0.f,0.f,0.f}, o1 = {0.f,0.f,0.f,0.f};
    {
        auto vaddr = [&](int kcv)->const short* {
            int tc = jlo + kcv*32 + q4*8;
            if (tc > T_SEQ-8) tc = T_SEQ-8;
            return vtb + qkv_base + (size_t)lr*T_SEQ + tc;
        };
        const short* va0 = vaddr(0);
        bf16x8 vb0 = *reinterpret_cast<const bf16x8*>(va0 + (size_t)(wave*16)*T_SEQ);
        bf16x8 vb1;
        if (wave < 2) vb1 = *reinterpret_cast<const bf16x8*>(va0 + (size_t)((wave+4)*16)*T_SEQ);
        for (int kc = 0; kc < WSLOT/32; ++kc) {
            bf16x8 n0, n1;
            if (kc + 1 < WSLOT/32) {
                const short* van = vaddr(kc + 1);
                n0 = *reinterpret_cast<const bf16x8*>(van + (size_t)(wave*16)*T_SEQ);
                if (wave < 2) n1 = *reinterpret_cast<const bf16x8*>(van + (size_t)((wave+4)*16)*T_SEQ);
            }
            const bf16x8 pa = *reinterpret_cast<const bf16x8*>(pb + lr*(2*W_P) + kc*32 + q4*8);
            o0 = MFMA16(pa, vb0, o0, 0, 0, 0);
            if (wave < 2) o1 = MFMA16(pa, vb1, o1, 0, 0, 0);
            vb0 = n0; vb1 = n1;
        }
    }
    __syncthreads();   // relv fully loaded

    // ---- epilogue: rel_v contribution + bf16 store to obtc[b][t][192]
    #pragma unroll
    for (int u = 0; u < 2; ++u) {
        if (u == 1 && wave >= 2) break;
        const int nt = (u == 0) ? wave : wave + 4;
        const f32x4 oc = (u == 0) ? o0 : o1;
        const int col = nt*16 + lr;
        #pragma unroll
        for (int e = 0; e < 4; ++e) {
            const int row = q4*4 + e;
            const int i = i0 + row;
            float v = oc[e];
            #pragma unroll
            for (int dd = 0; dd < 9; ++dd) {
                const int jg = i + dd - 4;
                if (jg >= 0 && jg < T_SEQ)
                    v += bfbits2f(pb[row*(2*W_P) + (jg - jlo)]) * shbuf[dd*K_DIM + col];
            }
            obtc[((size_t)b*T_SEQ + i)*C_DIM + h*K_DIM + col] = f2bf_bits(v);
        }
    }
}

// ---------------------------------------------------------------------------
// Kernel 3: output projection, bf16 MFMA, y^T form -> fp32 y[B,C,T].
// Grid 1024 (d-halves) -> 4 blocks/CU. Waves take tiles 2/2/1/1.
// ---------------------------------------------------------------------------
__global__ __launch_bounds__(256)
void oproj_kernel(const float* __restrict__ bo, float* __restrict__ y,
                  const char* __restrict__ ws)
{
    const int b    = blockIdx.x >> 8;
    const int half = (blockIdx.x >> 7) & 1;
    const int t0   = (blockIdx.x & 127) * 16;
    const int tid  = threadIdx.x;
    const int wave = tid >> 6, lane = tid & 63;
    const int q4 = lane >> 4, lr = lane & 15;

    const short* WoT  = (const short*)(ws + OFF_WT(3));
    const short* obtc = (const short*)(ws + OFF_OBTC);

    #pragma unroll
    for (int u = 0; u < 2; ++u) {
        if (u == 1 && wave >= 2) break;
        const int tl = (u == 0) ? wave : wave + 4;
        const int dt = half*6 + tl;
        f32x4 a = {0.f,0.f,0.f,0.f};
        #pragma unroll
        for (int kc = 0; kc < 6; ++kc) {
            const int ko = kc*32 + q4*8;
            const bf16x8 bf = *reinterpret_cast<const bf16x8*>(
                obtc + ((size_t)b*T_SEQ + t0 + lr)*C_DIM + ko);
            const bf16x8 af = *reinterpret_cast<const bf16x8*>(
                WoT + (dt*16 + lr)*C_DIM + ko);
            a = MFMA16(af, bf, a, 0, 0, 0);
        }
        #pragma unroll
        for (int e = 0; e < 4; ++e) {
            const int d = dt*16 + q4*4 + e;
            y[((size_t)b*C_DIM + d)*T_SEQ + t0 + lr] = a[e] + bo[d];
        }
    }
}

// ---------------------------------------------------------------------------
extern "C" void kernel_launch(void* const* d_in, const int* in_sizes, int n_in,
                              void* d_out, int out_size, void* d_ws, size_t ws_size,
                              hipStream_t stream)
{
    const float* x    = (const float*)d_in[0];
    const float* c    = (const float*)d_in[1];
    const float* Wq   = (const float*)d_in[2];
    const float* bq   = (const float*)d_in[3];
    const float* Wk   = (const float*)d_in[4];
    const float* bk   = (const float*)d_in[5];
    const float* Wv   = (const float*)d_in[6];
    const float* bv   = (const float*)d_in[7];
    const float* Wo   = (const float*)d_in[8];
    const float* bo   = (const float*)d_in[9];
    const float* relk = (const float*)d_in[10];
    const float* relv = (const float*)d_in[11];
    const int*   mask = (const int*)d_in[12];
    float*       y    = (float*)d_out;
    char*        ws   = (char*)d_ws;

    hipLaunchKernelGGL(prep_kernel, dim3(1121), dim3(256), 0, stream,
                       Wq, Wk, Wv, Wo, bq, relk, mask, ws);
    hipLaunchKernelGGL(proj_kernel, dim3(B_DIM*2*(T_SEQ/16)), dim3(256), 0, stream,
                       x, c, bk, bv, ws);
    hipLaunchKernelGGL(attn_kernel, dim3(B_DIM*H_DIM*(T_SEQ/IT)), dim3(256), 0, stream,
                       relv, ws);
    hipLaunchKernelGGL(oproj_kernel, dim3(B_DIM*2*(T_SEQ/16)), dim3(256), 0, stream,
                       bo, y, ws);
}